// Round 4
// baseline (1337.513 us; speedup 1.0000x reference)
//
#include <hip/hip_runtime.h>
#include <cstdint>
#include <cstddef>

// MemristorDense R15: verified-occupancy push + self-instrumenting probe.
// R14 pinned: fill 42us + harness overhead ~26us + k_prep ~3 + k_main ~18.
// Issue-cycle model says k_main floor ~11.4us (shared trans/VALU pipe); the
// ~30% gap is stalls. This round: k_main restructured for 8 waves/SIMD
// (VGPR<=64 via L-in-LDS uniform reads, CHUNK=64, 1024 real blocks = 4/CU),
// launch_bounds(512,8). Grid z extended 16->96: z<16 real output (exactly
// once, bit-preserved reduce order), z>=16 redo chunks z&15 into ws scratch
// -> the single 6x dispatch (~70-100us) finally surfaces k_main's
// VGPR/Occupancy/VALUBusy in top-5. Next round drops the probe passes.

#define B128 128
#define NIN  1024
#define NI   1025
#define NO   512
#define NJ   1024
#define GMIN 1.0e-5f
#define GSPAN (1.0e-3f - 1.0e-5f)
#define ZREAL 16     // real K-chunks over [0,1024)
#define ZTOT  96     // 16 real + 80 probe passes
#define CHUNK 64

__device__ __forceinline__ float flog2(float x) { return __builtin_amdgcn_logf(x); }
__device__ __forceinline__ float fexp2(float x) { return __builtin_amdgcn_exp2f(x); }

// Kernel 1 (grid 256 x 1024): zero out, LT[i][b]=1+log2(x[b][i]), block max -> bmax[256].
__global__ __launch_bounds__(1024) void k_prep(
    const float* __restrict__ x,
    const float* __restrict__ wp, const float* __restrict__ wn,
    const float* __restrict__ bp, const float* __restrict__ bn,
    float* __restrict__ LT, float* __restrict__ bmax, float* __restrict__ out)
{
    const int tid = blockIdx.x * 1024 + threadIdx.x;   // [0, 262144)

    if (tid < B128 * NO) out[tid] = 0.0f;

    if (tid < NI * B128) {
        int i = tid >> 7, b = tid & 127;
        float xv = (i < NIN) ? x[b * NIN + i] : 1.0f;
        LT[tid] = 1.0f + flog2(xv);                 // log2(2x); x=0 -> -inf (correct)
    }

    // NIN*NO = 524288 = 2 * 262144 exactly
    float m = fmaxf(fmaxf(__builtin_fabsf(wp[tid]), __builtin_fabsf(wn[tid])),
                    fmaxf(__builtin_fabsf(wp[tid + 262144]), __builtin_fabsf(wn[tid + 262144])));
    if (tid < NO) m = fmaxf(m, fmaxf(__builtin_fabsf(bp[tid]), __builtin_fabsf(bn[tid])));

    __shared__ float red[16];
    #pragma unroll
    for (int off = 32; off > 0; off >>= 1) m = fmaxf(m, __shfl_down(m, off, 64));
    if ((threadIdx.x & 63) == 0) red[threadIdx.x >> 6] = m;
    __syncthreads();
    if (threadIdx.x < 16) {
        m = red[threadIdx.x];
        #pragma unroll
        for (int off = 8; off > 0; off >>= 1) m = fmaxf(m, __shfl_down(m, off, 16));
        if (threadIdx.x == 0) bmax[blockIdx.x] = m;
    }
}

// Kernel 2: grid (8 o-tiles, 8 b-tiles, ZTOT) x 512 threads (8 waves).
// z<16: real chunk z -> out. z>=16: chunk z&15 -> scratch (probe).
// 1024 real blocks = 4/CU = 8 waves/SIMD (VGPR<=64 target: acc 32 + no L
// registers -- L tile lives in LDS, read via wave-uniform broadcast).
// Wave s: i = zc*64 + s + 8k, k in [0,8). 16 batches; per step 4 log2 +
// 32 exp2 (same trans total as R11). Diff-store reduce, order == R11.
__global__ __launch_bounds__(512, 8) void k_main(
    const float* __restrict__ nd,
    const float* __restrict__ wp, const float* __restrict__ wn,
    const float* __restrict__ bp, const float* __restrict__ bn,
    const float* __restrict__ LT, const float* __restrict__ bmax,
    float* __restrict__ out_real, float* __restrict__ out_probe)
{
    const int lane = threadIdx.x & 63;
    const int s    = threadIdx.x >> 6;      // wave id [0,8)
    const int o    = (blockIdx.x << 6) + lane;
    const int b0   = blockIdx.y << 4;       // 16 batches per block
    const int zc   = blockIdx.z & 15;       // chunk index [0,16)
    float* __restrict__ out = (blockIdx.z < ZREAL) ? out_real : out_probe;

    // reduce 256 per-block maxima (redundant per wave; L2-hot)
    float m = fmaxf(fmaxf(bmax[lane], bmax[lane + 64]),
                    fmaxf(bmax[lane + 128], bmax[lane + 192]));
    #pragma unroll
    for (int off = 32; off > 0; off >>= 1) m = fmaxf(m, __shfl_down(m, off, 64));
    const float maxw = __shfl(m, 0, 64);
    const float kG = GSPAN / maxw;
    const float C  = 0.5f * maxw / GSPAN;

    __shared__ float sL[CHUNK * 16];        // 4 KB: L[i_local][b_local]
    __shared__ float sR[512 * 17];          // 34816 B: diff partials, stride 17
    const int c0 = zc * CHUNK;

    // cooperative L-tile load: 1024 floats, 2 per thread
    {
        int e = threadIdx.x;
        #pragma unroll
        for (int q = 0; q < 2; ++q, e += 512) {
            const int li = e >> 4, lb = e & 15;
            sL[e] = LT[(size_t)(c0 + li) * B128 + b0 + lb];
        }
    }
    __syncthreads();

    const int i0 = c0 + s;
    const float* pnd = nd + (size_t)i0 * NJ + 2 * o;
    const float* pwp = wp + (size_t)i0 * NO + o;
    const float* pwn = wn + (size_t)i0 * NO + o;

    float accp[16], accn[16];
    #pragma unroll
    for (int j = 0; j < 16; ++j) { accp[j] = 0.0f; accn[j] = 0.0f; }

    // 1-deep prefetch on the lane-varying globals
    float2 nv = *(const float2*)pnd;
    float wvp = *pwp;
    float wvn = *pwn;

    #pragma unroll
    for (int k = 0; k < 8; ++k) {
        float2 nv_n; float wp_n, wn_n;
        if (k < 7) {
            pnd += 8 * NJ; pwp += 8 * NO; pwn += 8 * NO;
            nv_n = *(const float2*)pnd;
            wp_n = *pwp;
            wn_n = *pwn;
        }

        const float Ep = flog2(nv.x);
        const float En = flog2(nv.y);
        const float Wp = flog2(__builtin_fmaf(kG, __builtin_fabsf(wvp), GMIN));
        const float Wn = flog2(__builtin_fmaf(kG, __builtin_fabsf(wvn), GMIN));

        const int lbase = (s + 8 * k) * 16;
        #pragma unroll
        for (int q = 0; q < 4; ++q) {
            const float4 Lq = *(const float4*)(&sL[lbase + 4 * q]);   // uniform -> broadcast
            accp[4*q+0] += fexp2(__builtin_fmaf(Ep, Lq.x, Wp));
            accn[4*q+0] += fexp2(__builtin_fmaf(En, Lq.x, Wn));
            accp[4*q+1] += fexp2(__builtin_fmaf(Ep, Lq.y, Wp));
            accn[4*q+1] += fexp2(__builtin_fmaf(En, Lq.y, Wn));
            accp[4*q+2] += fexp2(__builtin_fmaf(Ep, Lq.z, Wp));
            accn[4*q+2] += fexp2(__builtin_fmaf(En, Lq.z, Wn));
            accp[4*q+3] += fexp2(__builtin_fmaf(Ep, Lq.w, Wp));
            accn[4*q+3] += fexp2(__builtin_fmaf(En, Lq.w, Wn));
        }

        if (k < 7) { nv = nv_n; wvp = wp_n; wvn = wn_n; }
    }

    // per-wave diff (same subtraction as R11's reduce, moved before store;
    // summation order across waves preserved). Stride 17: coprime w/ 32 banks.
    {
        const int base = (s * 64 + lane) * 17;
        #pragma unroll
        for (int j = 0; j < 16; ++j) sR[base + j] = accp[j] - accn[j];
    }
    __syncthreads();

    // bias row (i=1024): term = n * g, batch-independent; added by zc==0.
    float bias = 0.0f;
    if (zc == 0) {
        const float2 nb = *(const float2*)(nd + (size_t)NIN * NJ + 2 * o);
        const float gp = __builtin_fmaf(kG, __builtin_fabsf(bp[o]), GMIN);
        const float gn = __builtin_fmaf(kG, __builtin_fabsf(bn[o]), GMIN);
        bias = nb.x * gp - nb.y * gn;
    }

    #pragma unroll
    for (int r = 0; r < 2; ++r) {
        const int bb = s + (r << 3);       // [0,16)
        float sum = bias;
        #pragma unroll
        for (int w = 0; w < 8; ++w) sum += sR[(w * 64 + lane) * 17 + bb];
        unsafeAtomicAdd(out + (size_t)(b0 + bb) * NO + o, C * sum);
    }
}

extern "C" void kernel_launch(void* const* d_in, const int* in_sizes, int n_in,
                              void* d_out, int out_size, void* d_ws, size_t ws_size,
                              hipStream_t stream)
{
    const float* x  = (const float*)d_in[0];
    const float* wp = (const float*)d_in[1];
    const float* wn = (const float*)d_in[2];
    const float* bp = (const float*)d_in[3];
    const float* bn = (const float*)d_in[4];
    const float* nd = (const float*)d_in[5];
    float* out = (float*)d_out;

    unsigned char* ws = (unsigned char*)d_ws;
    float* bmax = (float*)ws;                 // 256 floats
    float* LT   = (float*)(ws + 4096);        // 1025*128*4 = 524800 B
    float* out_probe = (float*)(ws + (16u << 20));   // scratch for probe passes

    k_prep<<<256, 1024, 0, stream>>>(x, wp, wn, bp, bn, LT, bmax, out);
    k_main<<<dim3(8, 8, ZTOT), 512, 0, stream>>>(nd, wp, wn, bp, bn, LT, bmax,
                                                 out, out_probe);
}

// Round 5
// 94.585 us; speedup vs baseline: 14.1409x; 14.1409x over previous
//
#include <hip/hip_runtime.h>
#include <cstdint>
#include <cstddef>

// MemristorDense R16: hybrid trans/VALU exp2.
// R15 post-mortem: launch_bounds(512,8) spilled accs (VGPR=32, 2.6GB scratch
// writes, VALUBusy 7%) -- occupancy experiments via reg-cap are invalid.
// R13's clean 8-waves null + R11/R12/R13 invariance => k_main is bound by the
// transcendental unit (~16 cyc/wave64 exp2, ~15.4us of its 18us), VALU at 24%.
// This round: R11's proven structure, but 6 of 16 j-terms (both pos+neg, 12
// of 32 exp2/step) computed by an inline degree-5 poly exp2 on the VALU pipe
// (rndne reduce + 5 fma + exponent-insert + fma-accumulate). Pipe-balanced
// floor ~10.3us. Also the concurrency probe: if trans serializes with VALU
// issue this regresses slightly -> revert & ROOFLINE.

#define B128 128
#define NIN  1024
#define NI   1025
#define NO   512
#define NJ   1024
#define GMIN 1.0e-5f
#define GSPAN (1.0e-3f - 1.0e-5f)
#define ZCH  8      // K-chunks over [0,1024)
#define CHUNK 128

__device__ __forceinline__ float flog2(float x) { return __builtin_amdgcn_logf(x); }
__device__ __forceinline__ float fexp2(float x) { return __builtin_amdgcn_exp2f(x); }

// VALU-pipe exp2: acc += 2^u without touching the trans unit.
// u = E*L + W <= ~2.4 here; u can be -inf (x=0) -> clamp to -126 (result ~0).
__device__ __forceinline__ float fexp2_acc_valu(float u, float acc)
{
    u = fmaxf(u, -126.0f);
    const float n = __builtin_rintf(u);          // v_rndne_f32
    const float r = u - n;                       // |r| <= 0.5
    float p = __builtin_fmaf(r, 1.3333558146e-3f, 9.6181291076e-3f);
    p = __builtin_fmaf(r, p, 5.5504108665e-2f);
    p = __builtin_fmaf(r, p, 2.4022650696e-1f);
    p = __builtin_fmaf(r, p, 6.9314718056e-1f);
    p = __builtin_fmaf(r, p, 1.0f);
    const int ni = (int)n;
    const float s = __int_as_float((ni << 23) + 0x3f800000);  // 2^n
    return __builtin_fmaf(p, s, acc);
}

// Kernel 1 (grid 256 x 1024): zero out, LT[i][b]=1+log2(x[b][i]), block max -> bmax[256].
__global__ __launch_bounds__(1024) void k_prep(
    const float* __restrict__ x,
    const float* __restrict__ wp, const float* __restrict__ wn,
    const float* __restrict__ bp, const float* __restrict__ bn,
    float* __restrict__ LT, float* __restrict__ bmax, float* __restrict__ out)
{
    const int tid = blockIdx.x * 1024 + threadIdx.x;   // [0, 262144)

    if (tid < B128 * NO) out[tid] = 0.0f;

    if (tid < NI * B128) {
        int i = tid >> 7, b = tid & 127;
        float xv = (i < NIN) ? x[b * NIN + i] : 1.0f;
        LT[tid] = 1.0f + flog2(xv);                 // log2(2x); x=0 -> -inf (correct)
    }

    // NIN*NO = 524288 = 2 * 262144 exactly
    float m = fmaxf(fmaxf(__builtin_fabsf(wp[tid]), __builtin_fabsf(wn[tid])),
                    fmaxf(__builtin_fabsf(wp[tid + 262144]), __builtin_fabsf(wn[tid + 262144])));
    if (tid < NO) m = fmaxf(m, fmaxf(__builtin_fabsf(bp[tid]), __builtin_fabsf(bn[tid])));

    __shared__ float red[16];
    #pragma unroll
    for (int off = 32; off > 0; off >>= 1) m = fmaxf(m, __shfl_down(m, off, 64));
    if ((threadIdx.x & 63) == 0) red[threadIdx.x >> 6] = m;
    __syncthreads();
    if (threadIdx.x < 16) {
        m = red[threadIdx.x];
        #pragma unroll
        for (int off = 8; off > 0; off >>= 1) m = fmaxf(m, __shfl_down(m, off, 16));
        if (threadIdx.x == 0) bmax[blockIdx.x] = m;
    }
}

// Kernel 2: grid (8 o-tiles, 8 b-tiles, 8 K-chunks) x 512 threads (8 waves).
// R11 structure; inner loop hybrid: j<10 via trans-unit exp2, j>=10 via VALU
// polynomial (12 of 32 exp2/step on the otherwise-idle VALU pipe).
__global__ __launch_bounds__(512) void k_main(
    const float* __restrict__ nd,
    const float* __restrict__ wp, const float* __restrict__ wn,
    const float* __restrict__ bp, const float* __restrict__ bn,
    const float* __restrict__ LT, const float* __restrict__ bmax,
    float* __restrict__ out)
{
    const int lane = threadIdx.x & 63;
    const int s    = threadIdx.x >> 6;      // wave id [0,8)
    const int o    = (blockIdx.x << 6) + lane;
    const int b0   = blockIdx.y << 4;       // 16 batches per block

    // reduce 256 per-block maxima (redundant per wave; L2-hot)
    float m = fmaxf(fmaxf(bmax[lane], bmax[lane + 64]),
                    fmaxf(bmax[lane + 128], bmax[lane + 192]));
    #pragma unroll
    for (int off = 32; off > 0; off >>= 1) m = fmaxf(m, __shfl_down(m, off, 64));
    const float maxw = __shfl(m, 0, 64);
    const float kG = GSPAN / maxw;
    const float C  = 0.5f * maxw / GSPAN;

    const int i0 = blockIdx.z * CHUNK + s;   // this wave's first i

    const float* pnd = nd + (size_t)i0 * NJ + 2 * o;
    const float* pwp = wp + (size_t)i0 * NO + o;
    const float* pwn = wn + (size_t)i0 * NO + o;
    const float* pL  = LT + (size_t)i0 * B128 + b0;

    float accp[16], accn[16];
    #pragma unroll
    for (int k = 0; k < 16; ++k) { accp[k] = 0.0f; accn[k] = 0.0f; }

    // prologue loads for k=0
    float2 nv = *(const float2*)pnd;
    float wvp = *pwp;
    float wvn = *pwn;
    float4 La = *(const float4*)(pL);
    float4 Lb = *(const float4*)(pL + 4);
    float4 Lc = *(const float4*)(pL + 8);
    float4 Ld = *(const float4*)(pL + 12);

#define STEP() do { \
        const float Ep = flog2(nv.x); \
        const float En = flog2(nv.y); \
        const float Wp = flog2(__builtin_fmaf(kG, __builtin_fabsf(wvp), GMIN)); \
        const float Wn = flog2(__builtin_fmaf(kG, __builtin_fabsf(wvn), GMIN)); \
        const float Lv[16] = {La.x, La.y, La.z, La.w, Lb.x, Lb.y, Lb.z, Lb.w, \
                              Lc.x, Lc.y, Lc.z, Lc.w, Ld.x, Ld.y, Ld.z, Ld.w}; \
        _Pragma("unroll") \
        for (int j = 0; j < 10; ++j) { \
            accp[j] += fexp2(__builtin_fmaf(Ep, Lv[j], Wp)); \
            accn[j] += fexp2(__builtin_fmaf(En, Lv[j], Wn)); \
        } \
        _Pragma("unroll") \
        for (int j = 10; j < 16; ++j) { \
            accp[j] = fexp2_acc_valu(__builtin_fmaf(Ep, Lv[j], Wp), accp[j]); \
            accn[j] = fexp2_acc_valu(__builtin_fmaf(En, Lv[j], Wn), accn[j]); \
        } \
    } while (0)

    #pragma unroll 3
    for (int k = 0; k < 15; ++k) {
        pnd += 8 * NJ; pwp += 8 * NO; pwn += 8 * NO; pL += 8 * B128;
        float2 nv_n = *(const float2*)pnd;
        float wp_n = *pwp;
        float wn_n = *pwn;
        float4 Lan = *(const float4*)(pL);
        float4 Lbn = *(const float4*)(pL + 4);
        float4 Lcn = *(const float4*)(pL + 8);
        float4 Ldn = *(const float4*)(pL + 12);

        STEP();

        nv = nv_n; wvp = wp_n; wvn = wn_n;
        La = Lan; Lb = Lbn; Lc = Lcn; Ld = Ldn;
    }

    STEP();   // k = 15, no prefetch
#undef STEP

    // LDS reduce across the 8 waves. Row stride 33 floats -> conflict-free.
    __shared__ float lds[8 * 64 * 33];   // 67584 B
    {
        const int base = (s * 64 + lane) * 33;
        #pragma unroll
        for (int j = 0; j < 16; ++j) { lds[base + j] = accp[j]; lds[base + 16 + j] = accn[j]; }
    }
    __syncthreads();

    // bias row (i=1024): L=1 -> term = exp2(E+W) = n * g. Batch-independent;
    // added once per output by the z==0 blocks. Pure multiplies, no exp2.
    float bias = 0.0f;
    if (blockIdx.z == 0) {
        const float2 nb = *(const float2*)(nd + (size_t)NIN * NJ + 2 * o);
        const float gp = __builtin_fmaf(kG, __builtin_fabsf(bp[o]), GMIN);
        const float gn = __builtin_fmaf(kG, __builtin_fabsf(bn[o]), GMIN);
        bias = nb.x * gp - nb.y * gn;
    }

    {
        const int l = threadIdx.x & 63;
        #pragma unroll
        for (int r = 0; r < 2; ++r) {
            const int bb = (threadIdx.x >> 6) + (r << 3);   // [0,16)
            float sum = bias;
            #pragma unroll
            for (int w = 0; w < 8; ++w) {
                const int base = (w * 64 + l) * 33;
                sum += lds[base + bb] - lds[base + 16 + bb];
            }
            unsafeAtomicAdd(out + (size_t)(b0 + bb) * NO + (blockIdx.x << 6) + l, C * sum);
        }
    }
}

extern "C" void kernel_launch(void* const* d_in, const int* in_sizes, int n_in,
                              void* d_out, int out_size, void* d_ws, size_t ws_size,
                              hipStream_t stream)
{
    const float* x  = (const float*)d_in[0];
    const float* wp = (const float*)d_in[1];
    const float* wn = (const float*)d_in[2];
    const float* bp = (const float*)d_in[3];
    const float* bn = (const float*)d_in[4];
    const float* nd = (const float*)d_in[5];
    float* out = (float*)d_out;

    unsigned char* ws = (unsigned char*)d_ws;
    float* bmax = (float*)ws;                 // 256 floats
    float* LT   = (float*)(ws + 4096);        // 1025*128*4 = 524800 B

    k_prep<<<256, 1024, 0, stream>>>(x, wp, wn, bp, bn, LT, bmax, out);
    k_main<<<dim3(8, 8, ZCH), 512, 0, stream>>>(nd, wp, wn, bp, bn, LT, bmax, out);
}

// Round 6
// 87.927 us; speedup vs baseline: 15.2117x; 1.0757x over previous
//
#include <hip/hip_runtime.h>
#include <cstdint>
#include <cstddef>

// MemristorDense R17: REVERT to R11 (proven best, 88.3-88.9us).
// Session findings (R12-R16):
//  - R14 duplicate-dispatch probe: k_main = 18us, k_prep = 3us, fill = 42us,
//    invariant harness overhead = ~26us. Controllable budget ~21us of 88.9.
//  - R16 pipe-split probe: moving 12/32 exp2 to a VALU polynomial REGRESSED
//    (+5.7us) -> trans ops share the VALU issue stream (quarter-rate,
//    ~16 cyc/wave64). Serialized issue-cycle model predicts k_main at
//    19.1us vs 18 measured: k_main is AT its issue floor.
//  - exp2 count (134M = B*NIN*2*NO) is algebraically irreducible; occupancy
//    (R13), load restructuring (R12), table precompute (R12) all null.
// This is the floor for this structure; expecting ROOFLINE next round.

#define B128 128
#define NIN  1024
#define NI   1025
#define NO   512
#define NJ   1024
#define GMIN 1.0e-5f
#define GSPAN (1.0e-3f - 1.0e-5f)
#define ZCH  8      // K-chunks over [0,1024)
#define CHUNK 128

__device__ __forceinline__ float flog2(float x) { return __builtin_amdgcn_logf(x); }
__device__ __forceinline__ float fexp2(float x) { return __builtin_amdgcn_exp2f(x); }

// Kernel 1 (grid 256 x 1024): zero out, LT[i][b]=1+log2(x[b][i]), block max -> bmax[256].
__global__ __launch_bounds__(1024) void k_prep(
    const float* __restrict__ x,
    const float* __restrict__ wp, const float* __restrict__ wn,
    const float* __restrict__ bp, const float* __restrict__ bn,
    float* __restrict__ LT, float* __restrict__ bmax, float* __restrict__ out)
{
    const int tid = blockIdx.x * 1024 + threadIdx.x;   // [0, 262144)

    if (tid < B128 * NO) out[tid] = 0.0f;

    if (tid < NI * B128) {
        int i = tid >> 7, b = tid & 127;
        float xv = (i < NIN) ? x[b * NIN + i] : 1.0f;
        LT[tid] = 1.0f + flog2(xv);                 // log2(2x); x=0 -> -inf (correct)
    }

    // NIN*NO = 524288 = 2 * 262144 exactly
    float m = fmaxf(fmaxf(__builtin_fabsf(wp[tid]), __builtin_fabsf(wn[tid])),
                    fmaxf(__builtin_fabsf(wp[tid + 262144]), __builtin_fabsf(wn[tid + 262144])));
    if (tid < NO) m = fmaxf(m, fmaxf(__builtin_fabsf(bp[tid]), __builtin_fabsf(bn[tid])));

    __shared__ float red[16];
    #pragma unroll
    for (int off = 32; off > 0; off >>= 1) m = fmaxf(m, __shfl_down(m, off, 64));
    if ((threadIdx.x & 63) == 0) red[threadIdx.x >> 6] = m;
    __syncthreads();
    if (threadIdx.x < 16) {
        m = red[threadIdx.x];
        #pragma unroll
        for (int off = 8; off > 0; off >>= 1) m = fmaxf(m, __shfl_down(m, off, 16));
        if (threadIdx.x == 0) bmax[blockIdx.x] = m;
    }
}

// Kernel 2: grid (8 o-tiles, 8 b-tiles, 8 K-chunks) x 512 threads (8 waves).
// Wave s handles i = z*128 + s + 8k, k in [0,16) -- exactly 16 steps, no
// bounds checks. 16 batches/wave; per step: 4 log2 + 32 exp2. LDS reduce
// across 8 waves, bias (i=1024, pure mul) added by z==0 blocks, atomicAdd.
__global__ __launch_bounds__(512) void k_main(
    const float* __restrict__ nd,
    const float* __restrict__ wp, const float* __restrict__ wn,
    const float* __restrict__ bp, const float* __restrict__ bn,
    const float* __restrict__ LT, const float* __restrict__ bmax,
    float* __restrict__ out)
{
    const int lane = threadIdx.x & 63;
    const int s    = threadIdx.x >> 6;      // wave id [0,8)
    const int o    = (blockIdx.x << 6) + lane;
    const int b0   = blockIdx.y << 4;       // 16 batches per block

    // reduce 256 per-block maxima (redundant per wave; L2-hot)
    float m = fmaxf(fmaxf(bmax[lane], bmax[lane + 64]),
                    fmaxf(bmax[lane + 128], bmax[lane + 192]));
    #pragma unroll
    for (int off = 32; off > 0; off >>= 1) m = fmaxf(m, __shfl_down(m, off, 64));
    const float maxw = __shfl(m, 0, 64);
    const float kG = GSPAN / maxw;
    const float C  = 0.5f * maxw / GSPAN;

    const int i0 = blockIdx.z * CHUNK + s;   // this wave's first i

    const float* pnd = nd + (size_t)i0 * NJ + 2 * o;
    const float* pwp = wp + (size_t)i0 * NO + o;
    const float* pwn = wn + (size_t)i0 * NO + o;
    const float* pL  = LT + (size_t)i0 * B128 + b0;

    float accp[16], accn[16];
    #pragma unroll
    for (int k = 0; k < 16; ++k) { accp[k] = 0.0f; accn[k] = 0.0f; }

    // prologue loads for k=0
    float2 nv = *(const float2*)pnd;
    float wvp = *pwp;
    float wvn = *pwn;
    float4 La = *(const float4*)(pL);
    float4 Lb = *(const float4*)(pL + 4);
    float4 Lc = *(const float4*)(pL + 8);
    float4 Ld = *(const float4*)(pL + 12);

    #pragma unroll 3
    for (int k = 0; k < 15; ++k) {
        pnd += 8 * NJ; pwp += 8 * NO; pwn += 8 * NO; pL += 8 * B128;
        float2 nv_n = *(const float2*)pnd;
        float wp_n = *pwp;
        float wn_n = *pwn;
        float4 Lan = *(const float4*)(pL);
        float4 Lbn = *(const float4*)(pL + 4);
        float4 Lcn = *(const float4*)(pL + 8);
        float4 Ldn = *(const float4*)(pL + 12);

        const float Ep = flog2(nv.x);
        const float En = flog2(nv.y);
        const float Wp = flog2(__builtin_fmaf(kG, __builtin_fabsf(wvp), GMIN));
        const float Wn = flog2(__builtin_fmaf(kG, __builtin_fabsf(wvn), GMIN));

        const float Lv[16] = {La.x, La.y, La.z, La.w, Lb.x, Lb.y, Lb.z, Lb.w,
                              Lc.x, Lc.y, Lc.z, Lc.w, Ld.x, Ld.y, Ld.z, Ld.w};
        #pragma unroll
        for (int j = 0; j < 16; ++j) {
            accp[j] += fexp2(__builtin_fmaf(Ep, Lv[j], Wp));
            accn[j] += fexp2(__builtin_fmaf(En, Lv[j], Wn));
        }

        nv = nv_n; wvp = wp_n; wvn = wn_n;
        La = Lan; Lb = Lbn; Lc = Lcn; Ld = Ldn;
    }

    // last step (k=15), no prefetch
    {
        const float Ep = flog2(nv.x);
        const float En = flog2(nv.y);
        const float Wp = flog2(__builtin_fmaf(kG, __builtin_fabsf(wvp), GMIN));
        const float Wn = flog2(__builtin_fmaf(kG, __builtin_fabsf(wvn), GMIN));
        const float Lv[16] = {La.x, La.y, La.z, La.w, Lb.x, Lb.y, Lb.z, Lb.w,
                              Lc.x, Lc.y, Lc.z, Lc.w, Ld.x, Ld.y, Ld.z, Ld.w};
        #pragma unroll
        for (int j = 0; j < 16; ++j) {
            accp[j] += fexp2(__builtin_fmaf(Ep, Lv[j], Wp));
            accn[j] += fexp2(__builtin_fmaf(En, Lv[j], Wn));
        }
    }

    // LDS reduce across the 8 waves. Row stride 33 floats -> conflict-free.
    __shared__ float lds[8 * 64 * 33];   // 67584 B
    {
        const int base = (s * 64 + lane) * 33;
        #pragma unroll
        for (int j = 0; j < 16; ++j) { lds[base + j] = accp[j]; lds[base + 16 + j] = accn[j]; }
    }
    __syncthreads();

    // bias row (i=1024): L=1 -> term = exp2(E+W) = n * g. Batch-independent;
    // added once per output by the z==0 blocks. Pure multiplies, no exp2.
    float bias = 0.0f;
    if (blockIdx.z == 0) {
        const float2 nb = *(const float2*)(nd + (size_t)NIN * NJ + 2 * o);
        const float gp = __builtin_fmaf(kG, __builtin_fabsf(bp[o]), GMIN);
        const float gn = __builtin_fmaf(kG, __builtin_fabsf(bn[o]), GMIN);
        bias = nb.x * gp - nb.y * gn;
    }

    {
        const int l = threadIdx.x & 63;
        #pragma unroll
        for (int r = 0; r < 2; ++r) {
            const int bb = (threadIdx.x >> 6) + (r << 3);   // [0,16)
            float sum = bias;
            #pragma unroll
            for (int w = 0; w < 8; ++w) {
                const int base = (w * 64 + l) * 33;
                sum += lds[base + bb] - lds[base + 16 + bb];
            }
            unsafeAtomicAdd(out + (size_t)(b0 + bb) * NO + (blockIdx.x << 6) + l, C * sum);
        }
    }
}

extern "C" void kernel_launch(void* const* d_in, const int* in_sizes, int n_in,
                              void* d_out, int out_size, void* d_ws, size_t ws_size,
                              hipStream_t stream)
{
    const float* x  = (const float*)d_in[0];
    const float* wp = (const float*)d_in[1];
    const float* wn = (const float*)d_in[2];
    const float* bp = (const float*)d_in[3];
    const float* bn = (const float*)d_in[4];
    const float* nd = (const float*)d_in[5];
    float* out = (float*)d_out;

    unsigned char* ws = (unsigned char*)d_ws;
    float* bmax = (float*)ws;                 // 256 floats
    float* LT   = (float*)(ws + 4096);        // 1025*128*4 = 524800 B

    k_prep<<<256, 1024, 0, stream>>>(x, wp, wn, bp, bn, LT, bmax, out);
    k_main<<<dim3(8, 8, ZCH), 512, 0, stream>>>(nd, wp, wn, bp, bn, LT, bmax, out);
}